// Round 1
// baseline (495.791 us; speedup 1.0000x reference)
//
#include <hip/hip_runtime.h>

// ScannedLSTM: B=512, T=512, F=64, H=64 (4H=256 gate columns)
// Strategy: 1 block per batch row (512 blocks = 2 blocks/CU), 256 threads.
// Thread j holds Wi[:,j], Wh[:,j] in registers (128 VGPRs). Per step:
//   z_j = b_j + sum_k x[k]*wi[k] (+ sum_k h[k]*wh[k] unless reset) ,
// z -> LDS, wave0 computes gates + c/h update, h -> LDS (double-buffered).
// reset==1 skips the whole h@Wh accumulation (h masked to 0 in reference).

#define NB 512
#define NT 512
#define NF 64
#define NH 64
#define NG 256
#define TCHUNK 32

__device__ __forceinline__ float rcp_fast(float x) { return __builtin_amdgcn_rcpf(x); }
__device__ __forceinline__ float sig_fast(float x) { return rcp_fast(1.0f + __expf(-x)); }
__device__ __forceinline__ float tanh_fast(float x) {
    // tanh(x) = 1 - 2/(exp(2x)+1); saturates correctly at +-inf via rcp(inf)=0
    return 1.0f - 2.0f * rcp_fast(1.0f + __expf(2.0f * x));
}

// resets dtype detector: classifies the raw bit pattern of the resets array.
// flag bit1: saw 0x3F800000 (float 1.0)  -> float32 data
// flag bit2: saw a value outside {0,1,0x3F800000} -> packed uint8 data
// neither: clean int32 0/1 data
__global__ void detect_resets_dtype(const unsigned int* __restrict__ r, int n,
                                    int* __restrict__ flag) {
    int bits = 0;
    for (int i = blockIdx.x * blockDim.x + threadIdx.x; i < n;
         i += gridDim.x * blockDim.x) {
        unsigned v = r[i];
        if (v == 0x3F800000u) bits |= 2;
        else if (v != 0u && v != 1u) bits |= 4;
    }
    if (bits) atomicOr(flag, bits);
}

__global__ __launch_bounds__(256, 2)
void lstm_scan_kernel(const float* __restrict__ ins, const void* __restrict__ resets,
                      const float* __restrict__ Wi, const float* __restrict__ Wh,
                      const float* __restrict__ bias, float* __restrict__ out,
                      const int* __restrict__ flag) {
    const int b = blockIdx.x;
    const int j = threadIdx.x;  // gate column 0..255

    // resolve resets dtype mode: 0=int32, 1=uint8, 2=float32
    int mode = 0;
    if (flag) {
        int fl = *flag;
        if ((fl & 2) && !(fl & 4)) mode = 2;
        else if (fl & 4) mode = 1;
    }

    // per-thread weight columns in registers (static indices after full unroll)
    float wi[NF], wh[NF];
#pragma unroll
    for (int k = 0; k < NF; ++k) {
        wi[k] = Wi[k * NG + j];
        wh[k] = Wh[k * NG + j];
    }
    const float bj = bias[j];

    __shared__ __align__(16) float xs[TCHUNK][NF];   // staged x rows (8 KB)
    __shared__ int rs[TCHUNK];                       // staged decoded resets
    __shared__ __align__(16) float hbuf[2][NH];      // double-buffered h
    __shared__ float zbuf[NG];

    float c = 0.0f;  // cell state, owned by thread j < NH
    if (j < NH) { hbuf[0][j] = 0.0f; hbuf[1][j] = 0.0f; }
    __syncthreads();

    int cur = 0;
    for (int t0 = 0; t0 < NT; t0 += TCHUNK) {
        // stage TCHUNK x-rows: 2048 floats = 512 float4, 2 per thread, coalesced
        {
            const float4* src = (const float4*)(ins + ((size_t)b * NT + t0) * NF);
            float4* dst = (float4*)&xs[0][0];
            dst[j] = src[j];
            dst[j + 256] = src[j + 256];
            if (j < TCHUNK) {
                int idx = b * NT + t0 + j;
                int rv;
                if (mode == 1)      rv = ((const unsigned char*)resets)[idx] != 0;
                else if (mode == 2) rv = ((const float*)resets)[idx] != 0.0f;
                else                rv = ((const int*)resets)[idx] != 0;
                rs[j] = rv;
            }
        }
        __syncthreads();

        for (int tt = 0; tt < TCHUNK; ++tt) {
            const int t = t0 + tt;
            const int rst = rs[tt];

            float accx = bj;
            float acch = 0.0f;
            const float4* xv4 = (const float4*)&xs[tt][0];
#pragma unroll
            for (int k4 = 0; k4 < NF / 4; ++k4) {
                float4 xv = xv4[k4];  // LDS broadcast
                accx = fmaf(xv.x, wi[4 * k4 + 0], accx);
                accx = fmaf(xv.y, wi[4 * k4 + 1], accx);
                accx = fmaf(xv.z, wi[4 * k4 + 2], accx);
                accx = fmaf(xv.w, wi[4 * k4 + 3], accx);
            }
            if (!rst) {  // block-uniform branch: h==0 on reset, skip h@Wh entirely
                const float4* hv4 = (const float4*)&hbuf[cur][0];
#pragma unroll
                for (int k4 = 0; k4 < NF / 4; ++k4) {
                    float4 hv = hv4[k4];
                    acch = fmaf(hv.x, wh[4 * k4 + 0], acch);
                    acch = fmaf(hv.y, wh[4 * k4 + 1], acch);
                    acch = fmaf(hv.z, wh[4 * k4 + 2], acch);
                    acch = fmaf(hv.w, wh[4 * k4 + 3], acch);
                }
            }
            zbuf[j] = accx + acch;
            __syncthreads();

            if (j < NH) {  // gate phase: wave 0 only
                float zi = zbuf[j];
                float zf = zbuf[j + NH];
                float zg = zbuf[j + 2 * NH];
                float zo = zbuf[j + 3 * NH];
                float ig = sig_fast(zi);
                float fg = sig_fast(zf);
                float gg = tanh_fast(zg);
                float og = sig_fast(zo);
                float cc = rst ? 0.0f : c;
                cc = fg * cc + ig * gg;
                c = cc;
                float hh = og * tanh_fast(cc);
                hbuf[cur ^ 1][j] = hh;
                out[((size_t)b * NT + t) * NH + j] = hh;
            }
            __syncthreads();
            cur ^= 1;
        }
    }
}

extern "C" void kernel_launch(void* const* d_in, const int* in_sizes, int n_in,
                              void* d_out, int out_size, void* d_ws, size_t ws_size,
                              hipStream_t stream) {
    const float* ins    = (const float*)d_in[0];
    const void*  resets = d_in[1];
    const float* Wi     = (const float*)d_in[2];
    const float* Wh     = (const float*)d_in[3];
    const float* bias   = (const float*)d_in[4];
    float* out = (float*)d_out;

    int* flag = nullptr;
    if (d_ws && ws_size >= sizeof(int)) {
        flag = (int*)d_ws;
        hipMemsetAsync(flag, 0, sizeof(int), stream);
        detect_resets_dtype<<<256, 256, 0, stream>>>(
            (const unsigned int*)resets, NB * NT, flag);
    }

    lstm_scan_kernel<<<NB, 256, 0, stream>>>(ins, resets, Wi, Wh, bias, out, flag);
}